// Round 1
// baseline (247.186 us; speedup 1.0000x reference)
//
#include <hip/hip_runtime.h>
#include <math.h>

#define NSRC 2048
#define HID  1024
#define FSTR 72     // LDS row stride (bf16) for fourier stage
#define NBLK 512    // persistent grid: 2 blocks/CU on 256 CUs (co-resident)
#define NTHR 256

typedef __bf16 bf16_t;
typedef bf16_t bf16x8 __attribute__((ext_vector_type(8)));
typedef bf16_t bf16x4 __attribute__((ext_vector_type(4)));
typedef float  f32x4  __attribute__((ext_vector_type(4)));

__device__ __forceinline__ float gelu_f(float x) {
  float u = 0.7978845608028654f * x * (1.0f + 0.044715f * x * x);
  return 0.5f * x * (1.0f + tanhf(u));
}

// Device-scope grid barrier. Release RMW flushes this XCD's L2 (buffer_wbl2);
// acquire load invalidates (buffer_inv) so post-barrier reads see remote data.
// Monotonic counter, zeroed by the hipMemsetAsync before each launch.
__device__ __forceinline__ void grid_bar(unsigned* cnt, unsigned target) {
  __syncthreads();   // drains vmcnt: all block stores are in L2 before release
  if (threadIdx.x == 0) {
    __hip_atomic_fetch_add(cnt, 1u, __ATOMIC_RELEASE, __HIP_MEMORY_SCOPE_AGENT);
    while (__hip_atomic_load(cnt, __ATOMIC_RELAXED, __HIP_MEMORY_SCOPE_AGENT) < target)
      __builtin_amdgcn_s_sleep(2);
    (void)__hip_atomic_load(cnt, __ATOMIC_ACQUIRE, __HIP_MEMORY_SCOPE_AGENT);
  }
  __syncthreads();
}

// C = gelu(A @ B^T + bias). A (2048,1024), B (1024,1024), bf16 NT.
// Same structure as the standalone kernel: BM=BN=64, BK=64, reg-prefetch +
// LDS double-buffer, one barrier per k-step, XOR bank swizzle.
template <bool WRITE_C, bool COLSUM>
__device__ __forceinline__ void gemm_stage(
    const bf16_t* __restrict__ A, const bf16_t* __restrict__ B,
    const float* __restrict__ bias, bf16_t* __restrict__ C,
    float* __restrict__ hsum, bf16_t* Asb, bf16_t* Bsb, int tm, int tn) {
  const int K = 1024, NDIM = 1024;
  const int tid  = threadIdx.x;
  const int wave = tid >> 6;
  const int lane = tid & 63;
  const int wm = (wave & 1) * 32;
  const int wn = (wave >> 1) * 32;

  const int row0 = tid >> 3;
  const int pc   = tid & 7;
  const int lc   = pc ^ (row0 & 7);
  const bf16_t* gA = A + (size_t)(tm + row0) * K + lc * 8;
  const bf16_t* gB = B + (size_t)(tn + row0) * K + lc * 8;

  const int col15 = lane & 15;
  const int quad  = lane >> 4;
  const int rsw   = col15 & 7;
  f32x4 acc[2][2] = {};

  bf16x8 ra0 = *(const bf16x8*)(gA);
  bf16x8 ra1 = *(const bf16x8*)(gA + (size_t)32 * K);
  bf16x8 rb0 = *(const bf16x8*)(gB);
  bf16x8 rb1 = *(const bf16x8*)(gB + (size_t)32 * K);

#define COMPUTE_TILE(b)                                                        \
  do {                                                                         \
    _Pragma("unroll")                                                          \
    for (int s = 0; s < 2; ++s) {                                              \
      const int pck = (s * 4 + quad) ^ rsw;                                    \
      bf16x8 a0 = *(const bf16x8*)(&Asb[(b)*4096 + (wm + col15) * 64 + pck * 8]);      \
      bf16x8 a1 = *(const bf16x8*)(&Asb[(b)*4096 + (wm + 16 + col15) * 64 + pck * 8]); \
      bf16x8 b0 = *(const bf16x8*)(&Bsb[(b)*4096 + (wn + col15) * 64 + pck * 8]);      \
      bf16x8 b1 = *(const bf16x8*)(&Bsb[(b)*4096 + (wn + 16 + col15) * 64 + pck * 8]); \
      acc[0][0] = __builtin_amdgcn_mfma_f32_16x16x32_bf16(a0, b0, acc[0][0], 0, 0, 0); \
      acc[0][1] = __builtin_amdgcn_mfma_f32_16x16x32_bf16(a0, b1, acc[0][1], 0, 0, 0); \
      acc[1][0] = __builtin_amdgcn_mfma_f32_16x16x32_bf16(a1, b0, acc[1][0], 0, 0, 0); \
      acc[1][1] = __builtin_amdgcn_mfma_f32_16x16x32_bf16(a1, b1, acc[1][1], 0, 0, 0); \
    }                                                                          \
  } while (0)

  for (int k0 = 0; k0 < K; k0 += 64) {
    const int buf = (k0 >> 6) & 1;
    __syncthreads();
    *(bf16x8*)(&Asb[buf * 4096 + tid * 8])         = ra0;
    *(bf16x8*)(&Asb[buf * 4096 + (tid + 256) * 8]) = ra1;
    *(bf16x8*)(&Bsb[buf * 4096 + tid * 8])         = rb0;
    *(bf16x8*)(&Bsb[buf * 4096 + (tid + 256) * 8]) = rb1;
    if (k0 + 64 < K) {
      ra0 = *(const bf16x8*)(gA + k0 + 64);
      ra1 = *(const bf16x8*)(gA + (size_t)32 * K + k0 + 64);
      rb0 = *(const bf16x8*)(gB + k0 + 64);
      rb1 = *(const bf16x8*)(gB + (size_t)32 * K + k0 + 64);
    }
    if (k0 > 0) COMPUTE_TILE(buf ^ 1);
  }
  __syncthreads();
  COMPUTE_TILE(1);
#undef COMPUTE_TILE

  const int rq = quad * 4;
#pragma unroll
  for (int j = 0; j < 2; ++j) {
    const int col = tn + wn + j * 16 + col15;
    const float bj = bias[col];
    float cs = 0.0f;
#pragma unroll
    for (int i = 0; i < 2; ++i) {
      const int rbase = tm + wm + i * 16 + rq;
#pragma unroll
      for (int p = 0; p < 4; ++p) {
        float v = gelu_f(acc[i][j][p] + bj);
        if constexpr (WRITE_C) C[(size_t)(rbase + p) * NDIM + col] = (bf16_t)v;
        if constexpr (COLSUM) cs += v;
      }
    }
    if constexpr (COLSUM) {
      cs += __shfl_xor(cs, 16, 64);
      cs += __shfl_xor(cs, 32, 64);
      if (lane < 16) atomicAdd(&hsum[col], cs);
    }
  }
}

// One persistent kernel: head -> gemm1 -> gemm2+colsum -> gemv -> fourier,
// separated by device-scope grid barriers. Removes 4 dispatch boundaries.
__global__ __launch_bounds__(NTHR, 2) void fused_all(
    const float* __restrict__ sources, const float* __restrict__ r,
    const float* __restrict__ W1, const float* __restrict__ b1,
    const float* __restrict__ W2, const float* __restrict__ b2,
    const float* __restrict__ W3, const float* __restrict__ b3,
    const float* __restrict__ W4, const float* __restrict__ b4,
    const float* __restrict__ Wb, const float* __restrict__ bb,
    bf16_t* __restrict__ h1b, bf16_t* __restrict__ h2b,
    bf16_t* __restrict__ W2b, bf16_t* __restrict__ W3b,
    float* __restrict__ hsum, bf16_t* __restrict__ Wbig,
    float* __restrict__ bsum, unsigned* __restrict__ bar,
    float* __restrict__ out, int N) {
  extern __shared__ __align__(16) unsigned char smem[];   // 32 KB union
  bf16_t* Asb = (bf16_t*)smem;              // gemm: 2 x 8 KB
  bf16_t* Bsb = (bf16_t*)(smem + 16384);    // gemm: 2 x 8 KB
  const int tid = threadIdx.x;

  // ---- Stage A: h1 = gelu(sources @ W1.T + b1); W2/W3 -> bf16 ----
  {
    const int HALF = HID * HID / 4;   // 262144 float4s each
    for (int idx = blockIdx.x * NTHR + tid; idx < NSRC * HID; idx += NBLK * NTHR) {
      if (idx < 2 * HALF) {
        const float* src = (idx < HALF) ? W2 : W3;
        bf16_t* dst = (idx < HALF) ? W2b : W3b;
        int j = (idx < HALF) ? idx : idx - HALF;
        float4 v = ((const float4*)src)[j];
        bf16x4 o = {(bf16_t)v.x, (bf16_t)v.y, (bf16_t)v.z, (bf16_t)v.w};
        ((bf16x4*)dst)[j] = o;
      }
      int s = idx >> 10;
      int n = idx & (HID - 1);
      float4 src4 = *(const float4*)(sources + 4 * s);
      float4 w    = *(const float4*)(W1 + 4 * n);
      float z = src4.x * w.x + src4.y * w.y + src4.z * w.z + src4.w * w.w + b1[n];
      h1b[idx] = (bf16_t)gelu_f(z);
    }
  }
  grid_bar(bar, NBLK * 1);

  // XCD-swizzled tile mapping (consecutive blockIdx round-robin XCDs):
  // 8 regions of 8x8 tiles => ~2 MB working set per XCD L2.
  int tm, tn;
  {
    const int b = blockIdx.x;
    const int xcd = b & 7, j = b >> 3;            // j: 0..63
    tm = ((xcd >> 1) * 8 + (j >> 3)) * 64;        // 32 M-tiles
    tn = ((xcd & 1) * 8 + (j & 7)) * 64;          // 16 N-tiles
  }

  // ---- Stage B: h2 = gelu(h1 @ W2b.T + b2) ----
  gemm_stage<true, false>(h1b, W2b, b2, h2b, nullptr, Asb, Bsb, tm, tn);
  grid_bar(bar, NBLK * 2);

  // ---- Stage C: hsum += colsum(gelu(h2 @ W3b.T + b3)) ----
  gemm_stage<false, true>(h2b, W3b, b3, nullptr, hsum, Asb, Bsb, tm, tn);
  grid_bar(bar, NBLK * 3);

  // ---- Stage D: wsum = W4 @ hsum + S*b4 -> Wbig (bf16); bsum scalar ----
  for (int vb = blockIdx.x; vb <= 1024; vb += NBLK) {
    if (vb == 1024) {
      float a = 0.0f;
      float w0 = Wb[0], w1 = Wb[1], w2 = Wb[2], w3 = Wb[3];
      for (int s = tid; s < NSRC; s += NTHR) {
        float4 src = *(const float4*)(sources + 4 * s);
        a += src.x * w0 + src.y * w1 + src.z * w2 + src.w * w3;
      }
#pragma unroll
      for (int off = 32; off; off >>= 1) a += __shfl_down(a, off, 64);
      float* wred = (float*)smem;
      if ((tid & 63) == 0) wred[tid >> 6] = a;
      __syncthreads();
      if (tid == 0)
        bsum[0] = wred[0] + wred[1] + wred[2] + wred[3] + (float)NSRC * bb[0];
    } else {
      int o = vb * 4 + (tid >> 6);
      int lane = tid & 63;
      const float* row = W4 + (size_t)o * HID;
      float acc = 0.0f;
#pragma unroll
      for (int t = 0; t < 4; ++t) {
        float4 rv = *(const float4*)(row + t * 256 + lane * 4);
        float4 hv = *(const float4*)(hsum + t * 256 + lane * 4);
        acc = fmaf(rv.x, hv.x, acc);
        acc = fmaf(rv.y, hv.y, acc);
        acc = fmaf(rv.z, hv.z, acc);
        acc = fmaf(rv.w, hv.w, acc);
      }
#pragma unroll
      for (int off = 32; off; off >>= 1) acc += __shfl_down(acc, off, 64);
      if (lane == 0) {
        float val = acc + (float)NSRC * b4[o];
        int c = o >> 10, i5 = (o >> 5) & 31, j5 = o & 31;
        int m = i5 + (((c == 1) || (c == 3)) ? 32 : 0);
        int k = j5 + (((c == 1) || (c == 2)) ? 32 : 0);
        Wbig[m * 64 + k] = (bf16_t)val;
      }
    }
  }
  grid_bar(bar, NBLK * 4);

  // ---- Stage E: out[n] = bsum + x(n)^T (Wbig z(n)) ----
  {
    bf16_t* Ws = (bf16_t*)smem;           // 64 x FSTR
    bf16_t* Zs = Ws + 64 * FSTR;
    bf16_t* Xs = Zs + 64 * FSTR;          // total 27648 B <= 32 KB
    const int wave = tid >> 6;
    const int lane = tid & 63;
    const int nF = (N + 63) >> 6;
    bool wloaded = false;
    for (int vb = blockIdx.x; vb < nF; vb += NBLK) {
      __syncthreads();   // previous iteration's LDS readers done
      if (!wloaded) {
        const bf16x8* Wg = (const bf16x8*)Wbig;
        bf16x8 w0 = Wg[2 * tid], w1 = Wg[2 * tid + 1];
        int wrow = tid >> 2;
        int wcol = (tid & 3) * 16;
        *(bf16x8*)(Ws + wrow * FSTR + wcol) = w0;
        *(bf16x8*)(Ws + wrow * FSTR + wcol + 8) = w1;
        wloaded = true;
      }
      {
        const int p = tid >> 2, q = tid & 3;
        int n = vb * 64 + p;
        if (n >= N) n = N - 1;
        const float W0 = 0.6283185307179586f;   // 2*pi/10
        float xw = W0 * r[2 * n], yw = W0 * r[2 * n + 1];
        float a = (float)(q + 1);
        float s1x, c1x, s4x, c4x, s1y, c1y, s4y, c4y;
        sincosf(a * xw, &s1x, &c1x);
        sincosf(4.0f * xw, &s4x, &c4x);
        sincosf(a * yw, &s1y, &c1y);
        sincosf(4.0f * yw, &s4y, &c4y);
        float cxv = c1x, sxv = s1x, cyv = c1y, syv = s1y;
#pragma unroll
        for (int t = 0; t < 8; ++t) {
          int j = q + 4 * t;
          Zs[p * FSTR + j]      = (bf16_t)cyv;
          Zs[p * FSTR + 32 + j] = (bf16_t)syv;
          Xs[p * FSTR + j]      = (bf16_t)cxv;
          Xs[p * FSTR + 32 + j] = (bf16_t)sxv;
          float tc = cxv * c4x - sxv * s4x; sxv = sxv * c4x + cxv * s4x; cxv = tc;
          tc = cyv * c4y - syv * s4y; syv = syv * c4y + cyv * s4y; cyv = tc;
        }
      }
      __syncthreads();

      const int col15 = lane & 15;
      const int quad  = lane >> 4;
      const int q8    = quad * 8;
      f32x4 G[4] = {};
#pragma unroll
      for (int kc = 0; kc < 2; ++kc) {
        bf16x8 bz = *(const bf16x8*)(Zs + (wave * 16 + col15) * FSTR + kc * 32 + q8);
#pragma unroll
        for (int mt = 0; mt < 4; ++mt) {
          bf16x8 af = *(const bf16x8*)(Ws + (mt * 16 + col15) * FSTR + kc * 32 + q8);
          G[mt] = __builtin_amdgcn_mfma_f32_16x16x32_bf16(af, bz, G[mt], 0, 0, 0);
        }
      }

      const int pt = wave * 16 + col15;
      float s = 0.0f;
#pragma unroll
      for (int mt = 0; mt < 4; ++mt) {
        bf16x4 xv = *(const bf16x4*)(Xs + pt * FSTR + mt * 16 + quad * 4);
        s += (float)xv[0] * G[mt][0] + (float)xv[1] * G[mt][1] +
             (float)xv[2] * G[mt][2] + (float)xv[3] * G[mt][3];
      }
      s += __shfl_xor(s, 16, 64);
      s += __shfl_xor(s, 32, 64);
      if (lane < 16) {
        int n2 = vb * 64 + pt;
        if (n2 >= N) n2 = N - 1;
        out[n2] = s + bsum[0];
      }
    }
  }
}

extern "C" void kernel_launch(void* const* d_in, const int* in_sizes, int n_in,
                              void* d_out, int out_size, void* d_ws, size_t ws_size,
                              hipStream_t stream) {
  const float* sources = (const float*)d_in[0];
  const float* r   = (const float*)d_in[1];
  const float* W1  = (const float*)d_in[2];
  const float* b1  = (const float*)d_in[3];
  const float* W2  = (const float*)d_in[4];
  const float* b2  = (const float*)d_in[5];
  const float* W3  = (const float*)d_in[6];
  const float* b3  = (const float*)d_in[7];
  const float* W4  = (const float*)d_in[8];
  const float* b4  = (const float*)d_in[9];
  const float* Wb  = (const float*)d_in[10];
  const float* bb  = (const float*)d_in[11];
  float* out = (float*)d_out;

  char* ws = (char*)d_ws;
  bf16_t* h1b  = (bf16_t*)(ws);                         // 4 MB
  bf16_t* h2b  = (bf16_t*)(ws + (4 << 20));             // 4 MB
  bf16_t* W2b  = (bf16_t*)(ws + (8 << 20));             // 2 MB
  bf16_t* W3b  = (bf16_t*)(ws + (10 << 20));            // 2 MB
  char*   ctl  = ws + (12 << 20);                       // control block
  float*  hsum = (float*)(ctl);                         // 4 KB
  bf16_t* Wbig = (bf16_t*)(ctl + 4096);                 // 8 KB
  float*  bsum = (float*)(ctl + 12288);                 // 4 B
  unsigned* bar = (unsigned*)(ctl + 12292);             // 4 B

  int N = out_size;   // 100000 points

  // Zero hsum + barrier counter (graph-capturable; re-runs every replay).
  hipMemsetAsync(ctl, 0, 16384, stream);

  fused_all<<<NBLK, NTHR, 32768, stream>>>(
      sources, r, W1, b1, W2, b2, W3, b3, W4, b4, Wb, bb,
      h1b, h2b, W2b, W3b, hsum, Wbig, bsum, bar, out, N);
}

// Round 2
// 167.639 us; speedup vs baseline: 1.4745x; 1.4745x over previous
//
#include <hip/hip_runtime.h>
#include <math.h>

#define NSRC 2048
#define HID  1024
#define FSTR 72     // LDS row stride (bf16) for fourier stage
#define NBLK 512    // persistent grid: 2 blocks/CU on 256 CUs (co-resident)
#define NTHR 256

typedef __bf16 bf16_t;
typedef bf16_t bf16x8 __attribute__((ext_vector_type(8)));
typedef bf16_t bf16x4 __attribute__((ext_vector_type(4)));
typedef float  f32x4  __attribute__((ext_vector_type(4)));

__device__ __forceinline__ float gelu_f(float x) {
  float u = 0.7978845608028654f * x * (1.0f + 0.044715f * x * x);
  return 0.5f * x * (1.0f + tanhf(u));
}

// ---------------- cheap grid barrier ----------------
// Round-1's RELEASE/ACQUIRE atomics emitted buffer_wbl2 + buffer_inv (full L2
// tag walks) PER ARRIVING BLOCK: 4096 serialized walks ~= the 130us idle gap.
// This version: relaxed arrival counters; the LAST local arrival on each XCD
// does ONE buffer_wbl2 (flush local dirty data), bumps a done-counter, waits
// for all XCDs to flush, does ONE buffer_inv (drop stale lines), sets a go
// flag. 8 wbl2 + 8 inv per barrier, parallel across XCDs.
// Correctness: __syncthreads drains vmcnt per wave, so every block's stores
// are in its XCD L2 before its arrive-add; leader adds last => wbl2 flushes
// all local stores to the coherent point; inv precedes go => consumers refill
// fresh. Atomic counters are agent-coherent (bypass the inv'd caches).
// L1 staleness: no location is plain-read both before and after a barrier.

__device__ __forceinline__ unsigned rl(unsigned* p) {
  return __hip_atomic_load(p, __ATOMIC_RELAXED, __HIP_MEMORY_SCOPE_AGENT);
}
__device__ __forceinline__ unsigned radd(unsigned* p) {
  unsigned o = __hip_atomic_fetch_add(p, 1u, __ATOMIC_RELAXED,
                                      __HIP_MEMORY_SCOPE_AGENT);
  asm volatile("" ::"v"(o));   // force vmcnt drain: add completed before next op
  return o;
}

struct BarCtx {
  unsigned xcc, myTotal, nxcd, inited;
};

// B layout (u32 idx): [0..7]=totals  [8]=setup  [16+(p-1)*8+x]=arrive
//                     [48+(p-1)]=done  [56+(p-1)*8+x]=go    (p=1..4)
__device__ void grid_bar(unsigned* B, BarCtx& c, int phase) {
  __syncthreads();                 // all block stores vmcnt-drained, in L2
  if (threadIdx.x == 0) {
    if (!c.inited) {               // finish startup census (overlapped w/ stage A)
      while (rl(B + 8) < NBLK) __builtin_amdgcn_s_sleep(2);
      unsigned nx = 0, mt = 0;
      for (int x = 0; x < 8; ++x) {
        unsigned t = rl(B + x);
        nx += (t != 0);
        if ((unsigned)x == c.xcc) mt = t;
      }
      c.myTotal = mt; c.nxcd = nx; c.inited = 1;
    }
    unsigned old = radd(B + 16 + (phase - 1) * 8 + c.xcc);
    if (old == c.myTotal - 1) {    // last local arrival: I flush this XCD
      asm volatile("buffer_wbl2 sc1\n\ts_waitcnt vmcnt(0)" ::: "memory");
      radd(B + 48 + (phase - 1));
      while (rl(B + 48 + (phase - 1)) < c.nxcd) __builtin_amdgcn_s_sleep(2);
      asm volatile("buffer_inv sc1\n\ts_waitcnt vmcnt(0)" ::: "memory");
      __hip_atomic_store(B + 56 + (phase - 1) * 8 + c.xcc, 1u,
                         __ATOMIC_RELAXED, __HIP_MEMORY_SCOPE_AGENT);
    } else {
      while (rl(B + 56 + (phase - 1) * 8 + c.xcc) == 0)
        __builtin_amdgcn_s_sleep(2);
    }
  }
  __syncthreads();
}

// C = gelu(A @ B^T + bias). A (2048,1024), B (1024,1024), bf16 NT.
// BM=BN=64, BK=64, reg-prefetch + LDS double-buffer, one barrier per k-step,
// XOR bank swizzle. (Unchanged from the verified standalone kernel.)
template <bool WRITE_C, bool COLSUM>
__device__ __forceinline__ void gemm_stage(
    const bf16_t* __restrict__ A, const bf16_t* __restrict__ B,
    const float* __restrict__ bias, bf16_t* __restrict__ C,
    float* __restrict__ hsum, bf16_t* Asb, bf16_t* Bsb, int tm, int tn) {
  const int K = 1024, NDIM = 1024;
  const int tid  = threadIdx.x;
  const int wave = tid >> 6;
  const int lane = tid & 63;
  const int wm = (wave & 1) * 32;
  const int wn = (wave >> 1) * 32;

  const int row0 = tid >> 3;
  const int pc   = tid & 7;
  const int lc   = pc ^ (row0 & 7);
  const bf16_t* gA = A + (size_t)(tm + row0) * K + lc * 8;
  const bf16_t* gB = B + (size_t)(tn + row0) * K + lc * 8;

  const int col15 = lane & 15;
  const int quad  = lane >> 4;
  const int rsw   = col15 & 7;
  f32x4 acc[2][2] = {};

  bf16x8 ra0 = *(const bf16x8*)(gA);
  bf16x8 ra1 = *(const bf16x8*)(gA + (size_t)32 * K);
  bf16x8 rb0 = *(const bf16x8*)(gB);
  bf16x8 rb1 = *(const bf16x8*)(gB + (size_t)32 * K);

#define COMPUTE_TILE(b)                                                        \
  do {                                                                         \
    _Pragma("unroll")                                                          \
    for (int s = 0; s < 2; ++s) {                                              \
      const int pck = (s * 4 + quad) ^ rsw;                                    \
      bf16x8 a0 = *(const bf16x8*)(&Asb[(b)*4096 + (wm + col15) * 64 + pck * 8]);      \
      bf16x8 a1 = *(const bf16x8*)(&Asb[(b)*4096 + (wm + 16 + col15) * 64 + pck * 8]); \
      bf16x8 b0 = *(const bf16x8*)(&Bsb[(b)*4096 + (wn + col15) * 64 + pck * 8]);      \
      bf16x8 b1 = *(const bf16x8*)(&Bsb[(b)*4096 + (wn + 16 + col15) * 64 + pck * 8]); \
      acc[0][0] = __builtin_amdgcn_mfma_f32_16x16x32_bf16(a0, b0, acc[0][0], 0, 0, 0); \
      acc[0][1] = __builtin_amdgcn_mfma_f32_16x16x32_bf16(a0, b1, acc[0][1], 0, 0, 0); \
      acc[1][0] = __builtin_amdgcn_mfma_f32_16x16x32_bf16(a1, b0, acc[1][0], 0, 0, 0); \
      acc[1][1] = __builtin_amdgcn_mfma_f32_16x16x32_bf16(a1, b1, acc[1][1], 0, 0, 0); \
    }                                                                          \
  } while (0)

  for (int k0 = 0; k0 < K; k0 += 64) {
    const int buf = (k0 >> 6) & 1;
    __syncthreads();
    *(bf16x8*)(&Asb[buf * 4096 + tid * 8])         = ra0;
    *(bf16x8*)(&Asb[buf * 4096 + (tid + 256) * 8]) = ra1;
    *(bf16x8*)(&Bsb[buf * 4096 + tid * 8])         = rb0;
    *(bf16x8*)(&Bsb[buf * 4096 + (tid + 256) * 8]) = rb1;
    if (k0 + 64 < K) {
      ra0 = *(const bf16x8*)(gA + k0 + 64);
      ra1 = *(const bf16x8*)(gA + (size_t)32 * K + k0 + 64);
      rb0 = *(const bf16x8*)(gB + k0 + 64);
      rb1 = *(const bf16x8*)(gB + (size_t)32 * K + k0 + 64);
    }
    if (k0 > 0) COMPUTE_TILE(buf ^ 1);
  }
  __syncthreads();
  COMPUTE_TILE(1);
#undef COMPUTE_TILE

  const int rq = quad * 4;
#pragma unroll
  for (int j = 0; j < 2; ++j) {
    const int col = tn + wn + j * 16 + col15;
    const float bj = bias[col];
    float cs = 0.0f;
#pragma unroll
    for (int i = 0; i < 2; ++i) {
      const int rbase = tm + wm + i * 16 + rq;
#pragma unroll
      for (int p = 0; p < 4; ++p) {
        float v = gelu_f(acc[i][j][p] + bj);
        if constexpr (WRITE_C) C[(size_t)(rbase + p) * NDIM + col] = (bf16_t)v;
        if constexpr (COLSUM) cs += v;
      }
    }
    if constexpr (COLSUM) {
      cs += __shfl_xor(cs, 16, 64);
      cs += __shfl_xor(cs, 32, 64);
      if (lane < 16) atomicAdd(&hsum[col], cs);
    }
  }
}

// One persistent kernel: head -> gemm1 -> gemm2+colsum -> gemv -> fourier,
// separated by cheap XCD-aware grid barriers.
__global__ __launch_bounds__(NTHR, 2) void fused_all(
    const float* __restrict__ sources, const float* __restrict__ r,
    const float* __restrict__ W1, const float* __restrict__ b1,
    const float* __restrict__ W2, const float* __restrict__ b2,
    const float* __restrict__ W3, const float* __restrict__ b3,
    const float* __restrict__ W4, const float* __restrict__ b4,
    const float* __restrict__ Wb, const float* __restrict__ bb,
    bf16_t* __restrict__ h1b, bf16_t* __restrict__ h2b,
    bf16_t* __restrict__ W2b, bf16_t* __restrict__ W3b,
    float* __restrict__ hsum, bf16_t* __restrict__ Wbig,
    float* __restrict__ bsum, unsigned* __restrict__ bar,
    float* __restrict__ out, int N) {
  extern __shared__ __align__(16) unsigned char smem[];   // 32 KB union
  bf16_t* Asb = (bf16_t*)smem;              // gemm: 2 x 8 KB
  bf16_t* Bsb = (bf16_t*)(smem + 16384);    // gemm: 2 x 8 KB
  const int tid = threadIdx.x;

  BarCtx bc;
  {
    unsigned xcc;
    asm("s_getreg_b32 %0, hwreg(HW_REG_XCC_ID)" : "=s"(xcc));
    bc.xcc = xcc & 7; bc.inited = 0; bc.myTotal = 0; bc.nxcd = 0;
    if (tid == 0) {            // startup census; totals read at first barrier
      radd(bar + bc.xcc);      // totals[xcc]++
      radd(bar + 8);           // setup++
    }
  }

  // ---- Stage A: h1 = gelu(sources @ W1.T + b1); W2/W3 -> bf16 ----
  {
    const int HALF = HID * HID / 4;   // 262144 float4s each
    for (int idx = blockIdx.x * NTHR + tid; idx < NSRC * HID; idx += NBLK * NTHR) {
      if (idx < 2 * HALF) {
        const float* src = (idx < HALF) ? W2 : W3;
        bf16_t* dst = (idx < HALF) ? W2b : W3b;
        int j = (idx < HALF) ? idx : idx - HALF;
        float4 v = ((const float4*)src)[j];
        bf16x4 o = {(bf16_t)v.x, (bf16_t)v.y, (bf16_t)v.z, (bf16_t)v.w};
        ((bf16x4*)dst)[j] = o;
      }
      int s = idx >> 10;
      int n = idx & (HID - 1);
      float4 src4 = *(const float4*)(sources + 4 * s);
      float4 w    = *(const float4*)(W1 + 4 * n);
      float z = src4.x * w.x + src4.y * w.y + src4.z * w.z + src4.w * w.w + b1[n];
      h1b[idx] = (bf16_t)gelu_f(z);
    }
  }
  grid_bar(bar, bc, 1);

  // XCD-swizzled tile mapping (consecutive blockIdx round-robin XCDs):
  int tm, tn;
  {
    const int b = blockIdx.x;
    const int xcd = b & 7, j = b >> 3;            // j: 0..63
    tm = ((xcd >> 1) * 8 + (j >> 3)) * 64;        // 32 M-tiles
    tn = ((xcd & 1) * 8 + (j & 7)) * 64;          // 16 N-tiles
  }

  // ---- Stage B: h2 = gelu(h1 @ W2b.T + b2) ----
  gemm_stage<true, false>(h1b, W2b, b2, h2b, nullptr, Asb, Bsb, tm, tn);
  grid_bar(bar, bc, 2);

  // ---- Stage C: hsum += colsum(gelu(h2 @ W3b.T + b3)) ----
  gemm_stage<false, true>(h2b, W3b, b3, nullptr, hsum, Asb, Bsb, tm, tn);
  grid_bar(bar, bc, 3);

  // ---- Stage D: wsum = W4 @ hsum + S*b4 -> Wbig (bf16); bsum scalar ----
  for (int vb = blockIdx.x; vb <= 1024; vb += NBLK) {
    if (vb == 1024) {
      float a = 0.0f;
      float w0 = Wb[0], w1 = Wb[1], w2 = Wb[2], w3 = Wb[3];
      for (int s = tid; s < NSRC; s += NTHR) {
        float4 src = *(const float4*)(sources + 4 * s);
        a += src.x * w0 + src.y * w1 + src.z * w2 + src.w * w3;
      }
#pragma unroll
      for (int off = 32; off; off >>= 1) a += __shfl_down(a, off, 64);
      float* wred = (float*)smem;
      if ((tid & 63) == 0) wred[tid >> 6] = a;
      __syncthreads();
      if (tid == 0)
        bsum[0] = wred[0] + wred[1] + wred[2] + wred[3] + (float)NSRC * bb[0];
    } else {
      int o = vb * 4 + (tid >> 6);
      int lane = tid & 63;
      const float* row = W4 + (size_t)o * HID;
      float acc = 0.0f;
#pragma unroll
      for (int t = 0; t < 4; ++t) {
        float4 rv = *(const float4*)(row + t * 256 + lane * 4);
        float4 hv = *(const float4*)(hsum + t * 256 + lane * 4);
        acc = fmaf(rv.x, hv.x, acc);
        acc = fmaf(rv.y, hv.y, acc);
        acc = fmaf(rv.z, hv.z, acc);
        acc = fmaf(rv.w, hv.w, acc);
      }
#pragma unroll
      for (int off = 32; off; off >>= 1) acc += __shfl_down(acc, off, 64);
      if (lane == 0) {
        float val = acc + (float)NSRC * b4[o];
        int c = o >> 10, i5 = (o >> 5) & 31, j5 = o & 31;
        int m = i5 + (((c == 1) || (c == 3)) ? 32 : 0);
        int k = j5 + (((c == 1) || (c == 2)) ? 32 : 0);
        Wbig[m * 64 + k] = (bf16_t)val;
      }
    }
  }
  grid_bar(bar, bc, 4);

  // ---- Stage E: out[n] = bsum + x(n)^T (Wbig z(n)) ----
  {
    bf16_t* Ws = (bf16_t*)smem;           // 64 x FSTR
    bf16_t* Zs = Ws + 64 * FSTR;
    bf16_t* Xs = Zs + 64 * FSTR;          // total 27648 B <= 32 KB
    const int wave = tid >> 6;
    const int lane = tid & 63;
    const int nF = (N + 63) >> 6;
    bool wloaded = false;
    for (int vb = blockIdx.x; vb < nF; vb += NBLK) {
      __syncthreads();   // previous iteration's LDS readers done
      if (!wloaded) {
        const bf16x8* Wg = (const bf16x8*)Wbig;
        bf16x8 w0 = Wg[2 * tid], w1 = Wg[2 * tid + 1];
        int wrow = tid >> 2;
        int wcol = (tid & 3) * 16;
        *(bf16x8*)(Ws + wrow * FSTR + wcol) = w0;
        *(bf16x8*)(Ws + wrow * FSTR + wcol + 8) = w1;
        wloaded = true;
      }
      {
        const int p = tid >> 2, q = tid & 3;
        int n = vb * 64 + p;
        if (n >= N) n = N - 1;
        const float W0 = 0.6283185307179586f;   // 2*pi/10
        float xw = W0 * r[2 * n], yw = W0 * r[2 * n + 1];
        float a = (float)(q + 1);
        float s1x, c1x, s4x, c4x, s1y, c1y, s4y, c4y;
        sincosf(a * xw, &s1x, &c1x);
        sincosf(4.0f * xw, &s4x, &c4x);
        sincosf(a * yw, &s1y, &c1y);
        sincosf(4.0f * yw, &s4y, &c4y);
        float cxv = c1x, sxv = s1x, cyv = c1y, syv = s1y;
#pragma unroll
        for (int t = 0; t < 8; ++t) {
          int j = q + 4 * t;
          Zs[p * FSTR + j]      = (bf16_t)cyv;
          Zs[p * FSTR + 32 + j] = (bf16_t)syv;
          Xs[p * FSTR + j]      = (bf16_t)cxv;
          Xs[p * FSTR + 32 + j] = (bf16_t)sxv;
          float tc = cxv * c4x - sxv * s4x; sxv = sxv * c4x + cxv * s4x; cxv = tc;
          tc = cyv * c4y - syv * s4y; syv = syv * c4y + cyv * s4y; cyv = tc;
        }
      }
      __syncthreads();

      const int col15 = lane & 15;
      const int quad  = lane >> 4;
      const int q8    = quad * 8;
      f32x4 G[4] = {};
#pragma unroll
      for (int kc = 0; kc < 2; ++kc) {
        bf16x8 bz = *(const bf16x8*)(Zs + (wave * 16 + col15) * FSTR + kc * 32 + q8);
#pragma unroll
        for (int mt = 0; mt < 4; ++mt) {
          bf16x8 af = *(const bf16x8*)(Ws + (mt * 16 + col15) * FSTR + kc * 32 + q8);
          G[mt] = __builtin_amdgcn_mfma_f32_16x16x32_bf16(af, bz, G[mt], 0, 0, 0);
        }
      }

      const int pt = wave * 16 + col15;
      float s = 0.0f;
#pragma unroll
      for (int mt = 0; mt < 4; ++mt) {
        bf16x4 xv = *(const bf16x4*)(Xs + pt * FSTR + mt * 16 + quad * 4);
        s += (float)xv[0] * G[mt][0] + (float)xv[1] * G[mt][1] +
             (float)xv[2] * G[mt][2] + (float)xv[3] * G[mt][3];
      }
      s += __shfl_xor(s, 16, 64);
      s += __shfl_xor(s, 32, 64);
      if (lane < 16) {
        int n2 = vb * 64 + pt;
        if (n2 >= N) n2 = N - 1;
        out[n2] = s + bsum[0];
      }
    }
  }
}

extern "C" void kernel_launch(void* const* d_in, const int* in_sizes, int n_in,
                              void* d_out, int out_size, void* d_ws, size_t ws_size,
                              hipStream_t stream) {
  const float* sources = (const float*)d_in[0];
  const float* r   = (const float*)d_in[1];
  const float* W1  = (const float*)d_in[2];
  const float* b1  = (const float*)d_in[3];
  const float* W2  = (const float*)d_in[4];
  const float* b2  = (const float*)d_in[5];
  const float* W3  = (const float*)d_in[6];
  const float* b3  = (const float*)d_in[7];
  const float* W4  = (const float*)d_in[8];
  const float* b4  = (const float*)d_in[9];
  const float* Wb  = (const float*)d_in[10];
  const float* bb  = (const float*)d_in[11];
  float* out = (float*)d_out;

  char* ws = (char*)d_ws;
  bf16_t* h1b  = (bf16_t*)(ws);                         // 4 MB
  bf16_t* h2b  = (bf16_t*)(ws + (4 << 20));             // 4 MB
  bf16_t* W2b  = (bf16_t*)(ws + (8 << 20));             // 2 MB
  bf16_t* W3b  = (bf16_t*)(ws + (10 << 20));            // 2 MB
  char*   ctl  = ws + (12 << 20);                       // control block (16 KB)
  float*  hsum = (float*)(ctl);                         // 4 KB
  bf16_t* Wbig = (bf16_t*)(ctl + 4096);                 // 8 KB
  float*  bsum = (float*)(ctl + 12288);                 // 4 B
  unsigned* bar = (unsigned*)(ctl + 12352);             // barrier state (~352 B)

  int N = out_size;   // 100000 points

  // Zero hsum + barrier state (graph-capturable; re-runs every replay).
  hipMemsetAsync(ctl, 0, 16384, stream);

  fused_all<<<NBLK, NTHR, 32768, stream>>>(
      sources, r, W1, b1, W2, b2, W3, b3, W4, b4, Wb, bb,
      h1b, h2b, W2b, W3b, hsum, Wbig, bsum, bar, out, N);
}